// Round 7
// baseline (1387.703 us; speedup 1.0000x reference)
//
#include <hip/hip_runtime.h>
#include <hip/hip_bf16.h>
#include <stdint.h>

#define NN 50000
#define EE 100000
#define DD 768
#define MP 50176   // 196 * 256
#define KIN 96     // 78 padded to 96
#define SCB 196    // ceil(50000/256) scan blocks

typedef _Float16 half_t;
typedef __attribute__((ext_vector_type(8))) _Float16 v8h;
typedef __attribute__((ext_vector_type(4))) float v4f;

__device__ __forceinline__ void gload16(const half_t* g, half_t* l){
  __builtin_amdgcn_global_load_lds(
      (const __attribute__((address_space(1))) unsigned int*)(g),
      (__attribute__((address_space(3))) unsigned int*)(l),
      16, 0, 0);
}

// ================= 256x256 GEMM, K=768, BK=64 (conv / out-proj) =================
// 512 threads = 8 waves (2M x 4N), wave tile 128x64; 2 LDS buffers (128 KB);
// per iter: STAGE(i+1) issued first, counted vmcnt(8); 12 iters (barrier overhead halved).
// LDS swizzle: phys chunk = logical ^ (row&7)  (8 chunks of 16B per 128B row; <=2-way, free)
// MODE 1: conv     -> o16 = f16(acc)        (LDS-transpose epilogue, coalesced)
// MODE 2: out proj -> o32 = acc + bias      (fp32 direct stores, rows < NN)
template<int MODE>
__global__ __launch_bounds__(512, 2)
void gemm256_k(const half_t* __restrict__ A,
               const half_t* __restrict__ Bt,
               const float* __restrict__ bias,
               float* __restrict__ o32,
               half_t* __restrict__ o16)
{
  constexpr int K = 768;
  constexpr int NKT = 12;
  __shared__ __align__(16) half_t lds[2*32768];   // 2 bufs x (A 256x64 | B 256x64) = 128 KB

  // bijective XCD swizzle (m204), col-fastest (3 col-blocks share an A-tile)
  const int nwg = gridDim.x;
  const int q = nwg >> 3, r = nwg & 7;
  const int xcd = blockIdx.x & 7, ii = blockIdx.x >> 3;
  const int L = (xcd < r ? xcd*(q+1) : r*(q+1) + (xcd-r)*q) + ii;
  const int rowb = L / 3, colb = L - rowb*3;
  const int m0 = rowb*256, n0 = colb*256;

  const int t = threadIdx.x, l = t&63, w = t>>6;
  const int wm = w>>2, wn = w&3;       // wave tile = 128 x 64

  v4f acc[8][4];
  #pragma unroll
  for (int i=0;i<8;++i)
    #pragma unroll
    for (int j=0;j<4;++j){ v4f z = {0.f,0.f,0.f,0.f}; acc[i][j]=z; }

  // staging: instr j covers rows [64j,64j+64); lane writes row 64j+8w+(l>>3), phys chunk l&7.
  // source logical chunk = (l&7) ^ (row&7) = (l&7) ^ ((l>>3)&7)   (8w, 64j are 0 mod 8)
  const int sr = 8*w + (l>>3);
  const int sc = ((l&7) ^ ((l>>3)&7))*8;
  const half_t* Asrc = A  + (size_t)(m0 + sr)*K + sc;
  const half_t* Bsrc = Bt + (size_t)(n0 + sr)*K + sc;
  const int ldsbase = w*512;   // halfs; wave-uniform dest base (+ lane*16B by HW)

  auto STAGE = [&](int kt, int b){
    half_t* Ab = lds + b*32768;
    half_t* Bb = Ab + 16384;
    const int ko = kt*64;
    #pragma unroll
    for (int j=0;j<4;++j){
      gload16(Asrc + ko + (size_t)(64*j)*K, Ab + j*4096 + ldsbase);
      gload16(Bsrc + ko + (size_t)(64*j)*K, Bb + j*4096 + ldsbase);
    }
  };

  // fragment reads: row = base + m*16 + ra (base%8==0); logical chunk 4ks+hi;
  // phys = (4ks+hi) ^ (ra&7)
  const int ra = l&15, hi = l>>4;
  const int pc0 = (((0 + hi) ^ (ra&7)))*8;
  const int pc1 = (((4 + hi) ^ (ra&7)))*8;

  STAGE(0, 0);

  #pragma unroll
  for (int i=0;i<NKT;++i){
    if (i+1 < NKT){
      STAGE(i+1, (i+1)&1);                                  // issue early: latency spans whole iter
      asm volatile("s_waitcnt vmcnt(8)" ::: "memory");      // tile i landed; tile i+1 in flight
    } else {
      asm volatile("s_waitcnt vmcnt(0)" ::: "memory");
    }
    __builtin_amdgcn_s_barrier();

    const half_t* Ab = lds + (i&1)*32768;
    const half_t* Bb = Ab + 16384;
    v8h af[8][2], bf[4][2];
    #pragma unroll
    for (int n=0;n<4;++n){
      const half_t* rw_ = Bb + (wn*64 + n*16 + ra)*64;
      bf[n][0] = *(const v8h*)(rw_ + pc0);
      bf[n][1] = *(const v8h*)(rw_ + pc1);
    }
    #pragma unroll
    for (int m=0;m<8;++m){
      const half_t* rw_ = Ab + (wm*128 + m*16 + ra)*64;
      af[m][0] = *(const v8h*)(rw_ + pc0);
      af[m][1] = *(const v8h*)(rw_ + pc1);
    }

    __builtin_amdgcn_s_setprio(1);
    #pragma unroll
    for (int ks=0;ks<2;++ks)
      #pragma unroll
      for (int m=0;m<8;++m)
        #pragma unroll
        for (int n=0;n<4;++n)
          acc[m][n] = __builtin_amdgcn_mfma_f32_16x16x32_f16(af[m][ks], bf[n][ks], acc[m][n], 0,0,0);
    __builtin_amdgcn_s_setprio(0);

    asm volatile("s_waitcnt lgkmcnt(0)" ::: "memory");      // reads done before buffer reuse
    __builtin_amdgcn_s_barrier();
  }

  if (MODE==2){
    float bv[4];
    #pragma unroll
    for (int n=0;n<4;++n) bv[n] = bias[n0 + wn*64 + n*16 + ra];
    #pragma unroll
    for (int m=0;m<8;++m){
      #pragma unroll
      for (int rr=0;rr<4;++rr){
        int row = m0 + wm*128 + m*16 + (l>>4)*4 + rr;
        if (row >= NN) continue;
        #pragma unroll
        for (int n=0;n<4;++n){
          int col = n0 + wn*64 + n*16 + ra;
          o32[(size_t)row*DD + col] = acc[m][n][rr] + bv[n];
        }
      }
    }
  } else {
    // LDS-transpose epilogue, two 128-row passes (uses first 64 KB)
    #pragma unroll
    for (int p=0;p<2;++p){
      __syncthreads();
      if (wm==p){
        #pragma unroll
        for (int m=0;m<8;++m)
          #pragma unroll
          for (int rr=0;rr<4;++rr){
            int rw = m*16 + (l>>4)*4 + rr;
            #pragma unroll
            for (int n=0;n<4;++n){
              int col = wn*64 + n*16 + ra;
              lds[rw*256 + (col ^ ((rw&15)<<3))] = (half_t)acc[m][n][rr];
            }
          }
      }
      __syncthreads();
      #pragma unroll
      for (int g=0; g<8; ++g){
        int rw = (t>>5) + g*16;
        int colB = (t&31)*8;
        v8h hv = *(const v8h*)(lds + rw*256 + (colB ^ ((rw&15)<<3)));
        *(v8h*)(o16 + (size_t)(m0 + p*128 + rw)*DD + n0 + colB) = hv;
      }
    }
  }
}

// ================= 128x128 GEMM (input proj, K=96) =================
__global__ __launch_bounds__(256)
void gemm128_k(const half_t* __restrict__ A,
               const half_t* __restrict__ Bt,
               int K,
               const float* __restrict__ bias,
               half_t* __restrict__ o16)
{
  __shared__ __align__(16) half_t smem[128*128];
  half_t* As = smem;
  half_t* Bs = smem + 128*32;
  const int nwg = gridDim.x;
  const int q = nwg >> 3, r = nwg & 7;
  const int xcd = blockIdx.x & 7, ii = blockIdx.x >> 3;
  const int L = (xcd < r ? xcd*(q+1) : r*(q+1) + (xcd-r)*q) + ii;
  const int rowb = L / 6, colb = L - rowb*6;
  const int m0 = rowb*128, n0 = colb*128;

  const int t = threadIdx.x, l = t&63, w = t>>6;
  const int wr = w>>1, wc = w&1;
  v4f acc[4][4];
  #pragma unroll
  for (int i=0;i<4;++i)
    #pragma unroll
    for (int j=0;j<4;++j){ v4f z = {0.f,0.f,0.f,0.f}; acc[i][j]=z; }

  const int nkt = K/32;
  for (int kt=0; kt<nkt; ++kt){
    __syncthreads();
    #pragma unroll
    for (int j=0;j<2;++j){
      int br  = w*32 + j*16;
      int row = br + (l>>2);
      int ch  = (l&3) ^ ((row>>1)&3);
      gload16(A  + (size_t)(m0+row)*K + kt*32 + ch*8, As + br*32);
      gload16(Bt + (size_t)(n0+row)*K + kt*32 + ch*8, Bs + br*32);
    }
    __syncthreads();
    v8h af[4], bf[4];
    #pragma unroll
    for (int m=0;m<4;++m){
      int row = wr*64 + m*16 + (l&15);
      int ch = (l>>4) ^ ((row>>1)&3);
      af[m] = *(const v8h*)(As + row*32 + ch*8);
    }
    #pragma unroll
    for (int n=0;n<4;++n){
      int row = wc*64 + n*16 + (l&15);
      int ch = (l>>4) ^ ((row>>1)&3);
      bf[n] = *(const v8h*)(Bs + row*32 + ch*8);
    }
    #pragma unroll
    for (int m=0;m<4;++m)
      #pragma unroll
      for (int n=0;n<4;++n)
        acc[m][n] = __builtin_amdgcn_mfma_f32_16x16x32_f16(af[m], bf[n], acc[m][n], 0,0,0);
  }

  __syncthreads();
  #pragma unroll
  for (int m=0;m<4;++m){
    #pragma unroll
    for (int rr=0;rr<4;++rr){
      int row = wr*64 + m*16 + (l>>4)*4 + rr;
      #pragma unroll
      for (int n=0;n<4;++n){
        int colL = wc*64 + n*16 + (l&15);
        float v = acc[m][n][rr] + bias[n0+colL];
        int col = colL ^ (((row>>2)&3)<<4);
        smem[row*128 + col] = (half_t)v;
      }
    }
  }
  __syncthreads();
  #pragma unroll
  for (int c=0;c<8;++c){
    int row = c*16 + (t>>4);
    int colBase = (t&15)*8;
    int col = colBase ^ (((row>>2)&3)<<4);
    v8h hv = *(const v8h*)(smem + row*128 + col);
    *(v8h*)(o16 + (size_t)(m0+row)*DD + n0 + colBase) = hv;
  }
}

// ---------------- degree / CSR build ----------------
__global__ void k_count(const int* __restrict__ dst, int* __restrict__ cnt){
  int e = blockIdx.x*256 + threadIdx.x;
  if (e < EE) atomicAdd(&cnt[dst[e]], 1);
}
__global__ void k_dinv(const int* __restrict__ cnt, float* __restrict__ dinv){
  int i = blockIdx.x*256 + threadIdx.x;
  if (i < MP) dinv[i] = (i < NN) ? rsqrtf((float)cnt[i] + 1.0f) : 0.f;
}
__global__ void k_bsum(const int* __restrict__ cnt, int* __restrict__ bsum){
  int i = blockIdx.x*256 + threadIdx.x;
  int v = (i < NN) ? cnt[i] : 0;
  #pragma unroll
  for (int o=1;o<64;o<<=1) v += __shfl_xor(v, o);
  __shared__ int ws_[4];
  if ((threadIdx.x&63)==0) ws_[threadIdx.x>>6] = v;
  __syncthreads();
  if (threadIdx.x==0) bsum[blockIdx.x] = ws_[0]+ws_[1]+ws_[2]+ws_[3];
}
__global__ void k_btop(const int* __restrict__ bsum, int* __restrict__ boff){
  if (threadIdx.x==0){
    int run = 0;
    for (int b=0;b<SCB;++b){ boff[b] = run; run += bsum[b]; }
  }
}
__global__ void k_rowptr(const int* __restrict__ cnt, const int* __restrict__ boff,
                         int* __restrict__ rowptr, int* __restrict__ cursor){
  __shared__ int sh[256];
  int i = blockIdx.x*256 + threadIdx.x;
  int v = (i < NN) ? cnt[i] : 0;
  sh[threadIdx.x] = v; __syncthreads();
  #pragma unroll
  for (int o=1;o<256;o<<=1){
    int add = 0;
    if (threadIdx.x >= o) add = sh[threadIdx.x - o];
    __syncthreads();
    sh[threadIdx.x] += add;
    __syncthreads();
  }
  int excl = sh[threadIdx.x] - v + boff[blockIdx.x];
  if (i <= NN) rowptr[i] = excl;
  if (i < NN)  cursor[i] = excl;
}
__global__ void k_fill(const int* __restrict__ src, const int* __restrict__ dst,
                       const float* __restrict__ dinv, int* __restrict__ cursor,
                       int* __restrict__ ss, float* __restrict__ we){
  int e = blockIdx.x*256 + threadIdx.x;
  if (e < EE){
    int s = src[e], d = dst[e];
    int pos = atomicAdd(&cursor[d], 1);
    ss[pos] = s;
    we[pos] = dinv[s]*dinv[d];
  }
}
__global__ void k_x16(const float* __restrict__ x, half_t* __restrict__ x16){
  int idx = blockIdx.x*256 + threadIdx.x;
  if (idx < MP*KIN){
    int row = idx / KIN, k = idx - row*KIN;
    float v = (row < NN && k < 78) ? x[(size_t)row*78 + k] : 0.f;
    x16[idx] = (half_t)v;
  }
}
__global__ void k_tr(const float* __restrict__ src, half_t* __restrict__ dst, int K, int ldk){
  int idx = blockIdx.x*256 + threadIdx.x;
  if (idx < DD*ldk){
    int n = idx / ldk, k = idx - n*ldk;
    dst[idx] = (k < K) ? (half_t)src[(size_t)k*DD + n] : (half_t)0.f;
  }
}

// ---------------- CSR gather: agg16 = f16(bias + dinv^2*xw[d] + sum en*xw[src]); fused BN stats ----------------
__global__ __launch_bounds__(256)
void k_gather(const int* __restrict__ rowptr, const int* __restrict__ ss,
              const float* __restrict__ we, const half_t* __restrict__ xw,
              const float* __restrict__ dinv, const float* __restrict__ bias,
              half_t* __restrict__ agg16, float* __restrict__ stats){
  const int t = threadIdx.x;
  const float b0 = bias[t], b1 = bias[t+256], b2 = bias[t+512];
  float s0=0,s1=0,s2=0,q0=0,q1=0,q2=0;
  for (int d = blockIdx.x; d < NN; d += gridDim.x){
    int beg = rowptr[d], end = rowptr[d+1];
    float dv = dinv[d], sn = dv*dv;
    const half_t* xr = xw + (size_t)d*DD;
    float a0 = fmaf(sn, (float)xr[t    ], b0);
    float a1 = fmaf(sn, (float)xr[t+256], b1);
    float a2 = fmaf(sn, (float)xr[t+512], b2);
    int e = beg;
    for (; e+1 < end; e += 2){       // 2-edge unroll: 6 independent loads in flight
      int sA = ss[e], sB = ss[e+1];
      float wA = we[e], wB = we[e+1];
      const half_t* xA = xw + (size_t)sA*DD;
      const half_t* xB = xw + (size_t)sB*DD;
      float uA0 = (float)xA[t], uA1 = (float)xA[t+256], uA2 = (float)xA[t+512];
      float uB0 = (float)xB[t], uB1 = (float)xB[t+256], uB2 = (float)xB[t+512];
      a0 += wA*uA0 + wB*uB0;
      a1 += wA*uA1 + wB*uB1;
      a2 += wA*uA2 + wB*uB2;
    }
    if (e < end){
      int sA = ss[e]; float wA = we[e];
      const half_t* xA = xw + (size_t)sA*DD;
      a0 = fmaf(wA, (float)xA[t    ], a0);
      a1 = fmaf(wA, (float)xA[t+256], a1);
      a2 = fmaf(wA, (float)xA[t+512], a2);
    }
    half_t* ar = agg16 + (size_t)d*DD;
    ar[t] = (half_t)a0; ar[t+256] = (half_t)a1; ar[t+512] = (half_t)a2;
    s0 += a0; q0 += a0*a0;
    s1 += a1; q1 += a1*a1;
    s2 += a2; q2 += a2*a2;
  }
  atomicAdd(&stats[t],        s0); atomicAdd(&stats[t+256],     s1); atomicAdd(&stats[t+512],     s2);
  atomicAdd(&stats[DD+t],     q0); atomicAdd(&stats[DD+t+256],  q1); atomicAdd(&stats[DD+t+512],  q2);
}

__global__ void k_final(const float* __restrict__ stats, const float* __restrict__ g,
                        const float* __restrict__ b, float* __restrict__ sc, float* __restrict__ sh){
  int t = threadIdx.x;
  #pragma unroll
  for (int j=0;j<3;++j){
    int d = t + j*256;
    float mu  = stats[d]      * (1.0f/NN);
    float msq = stats[DD+d]   * (1.0f/NN);
    float var = msq - mu*mu;
    float rstd = rsqrtf(var + 1e-5f);
    float scale = rstd * g[d];
    sc[d] = scale;
    sh[d] = b[d] - mu*scale;
  }
}
// h16 += relu(agg*sc + sh)   (fp16 residual state)
__global__ void k_apply(const half_t* __restrict__ agg16, const float* __restrict__ sc,
                        const float* __restrict__ sh, half_t* __restrict__ h16){
  const int total = NN*DD/8;
  for (int i = blockIdx.x*blockDim.x + threadIdx.x; i < total; i += gridDim.x*blockDim.x){
    size_t base = (size_t)i*8;
    int col = (int)(base % DD);
    v8h a = *(const v8h*)(agg16 + base);
    v8h h = *(const v8h*)(h16 + base);
    v8h o;
    #pragma unroll
    for (int j=0;j<8;++j){
      float v = fmaxf(fmaf((float)a[j], sc[col+j], sh[col+j]), 0.f);
      o[j] = (half_t)((float)h[j] + v);
    }
    *(v8h*)(h16 + base) = o;
  }
}

extern "C" void kernel_launch(void* const* d_in, const int* in_sizes, int n_in,
                              void* d_out, int out_size, void* d_ws, size_t ws_size,
                              hipStream_t stream){
  (void)in_sizes; (void)n_in; (void)out_size; (void)ws_size;
  const float* x      = (const float*)d_in[0];
  const int*   ei     = (const int*)  d_in[1];
  const float* in_w   = (const float*)d_in[2];
  const float* in_b   = (const float*)d_in[3];
  const float* conv_w = (const float*)d_in[4];
  const float* conv_b = (const float*)d_in[5];
  const float* bn_g   = (const float*)d_in[6];
  const float* bn_b   = (const float*)d_in[7];
  const float* out_w  = (const float*)d_in[8];
  const float* out_b  = (const float*)d_in[9];
  float* out = (float*)d_out;
  const int* srcI = ei;
  const int* dstI = ei + EE;

  char* ws = (char*)d_ws; size_t off = 0;
  auto alloc = [&](size_t b)->void*{ void* p = ws + off; off += (b + 255) & ~(size_t)255; return p; };
  half_t* h16  = (half_t*)alloc((size_t)MP*DD*2);
  half_t* xw16 = (half_t*)alloc((size_t)MP*DD*2);
  half_t* agg16= (half_t*)alloc((size_t)NN*DD*2);
  half_t* x16  = (half_t*)alloc((size_t)MP*KIN*2);
  half_t* wT   = (half_t*)alloc((size_t)(DD*KIN + 6*DD*DD)*2);
  float* dinv   = (float*)alloc((size_t)MP*4);
  int*   cnt    = (int*)  alloc((size_t)MP*4);
  int*   rowptr = (int*)  alloc((size_t)(NN+1)*4);
  int*   cursor = (int*)  alloc((size_t)NN*4);
  int*   ssE    = (int*)  alloc((size_t)EE*4);
  float* weE    = (float*)alloc((size_t)EE*4);
  int*   bsum   = (int*)  alloc((size_t)SCB*4);
  int*   boff   = (int*)  alloc((size_t)SCB*4);
  float* stats  = (float*)alloc((size_t)4*DD*4);

  half_t* wTin = wT;
  half_t* wTc  = wT + DD*KIN;
  half_t* wTo  = wTc + 5*DD*DD;

  hipMemsetAsync(cnt, 0, (size_t)MP*4, stream);
  k_count<<<(EE+255)/256,256,0,stream>>>(dstI, cnt);
  k_dinv <<<(MP+255)/256,256,0,stream>>>(cnt, dinv);
  k_bsum <<<SCB,256,0,stream>>>(cnt, bsum);
  k_btop <<<1,64,0,stream>>>(bsum, boff);
  k_rowptr<<<SCB,256,0,stream>>>(cnt, boff, rowptr, cursor);
  k_fill <<<(EE+255)/256,256,0,stream>>>(srcI, dstI, dinv, cursor, ssE, weE);
  k_x16  <<<(MP*KIN+255)/256,256,0,stream>>>(x, x16);
  k_tr   <<<(DD*KIN+255)/256,256,0,stream>>>(in_w, wTin, 78, KIN);
  for (int l = 0; l < 5; ++l)
    k_tr <<<(DD*DD+255)/256,256,0,stream>>>(conv_w + (size_t)l*DD*DD, wTc + (size_t)l*DD*DD, DD, DD);
  k_tr   <<<(DD*DD+255)/256,256,0,stream>>>(out_w, wTo, DD, DD);

  const int NWG1 = (MP/128)*(DD/128);
  gemm128_k<<<NWG1,256,0,stream>>>(x16, wTin, KIN, in_b, h16);

  const int NWG2 = (MP/256)*(DD/256);   // 196*3 = 588
  for (int l = 0; l < 5; ++l){
    gemm256_k<1><<<NWG2,512,0,stream>>>(h16, wTc + (size_t)l*DD*DD, nullptr, nullptr, xw16);
    hipMemsetAsync(stats, 0, (size_t)2*DD*4, stream);
    k_gather<<<2048,256,0,stream>>>(rowptr, ssE, weE, xw16, dinv, conv_b + l*DD, agg16, stats);
    k_final<<<1,256,0,stream>>>(stats, bn_g + l*DD, bn_b + l*DD, stats+2*DD, stats+3*DD);
    k_apply<<<2048,256,0,stream>>>(agg16, stats+2*DD, stats+3*DD, h16);
  }

  gemm256_k<2><<<NWG2,512,0,stream>>>(h16, wTo, out_b, out, nullptr);
}